// Round 2
// baseline (748.932 us; speedup 1.0000x reference)
//
#include <hip/hip_runtime.h>

#define NN 20000      // nodes
#define NE 640000     // edges (without self loops)
#define NEE 660000    // edges + self loops
#define NP 200000     // drug pairs
#define NEG 0.2f      // leaky relu slope

// ---------------- CSR build ----------------
__global__ void k_hist(const int* __restrict__ ei, int* __restrict__ cnt) {
  int i = blockIdx.x * 256 + threadIdx.x;
  if (i >= NEE) return;
  int d = (i < NE) ? ei[NE + i] : (i - NE);
  atomicAdd(&cnt[d], 1);
}

__global__ void k_scan(const int* __restrict__ cnt, int* __restrict__ rp) {
  __shared__ int ps[256];
  const int CH = 79;  // 79*256 = 20224 >= 20000
  int t = threadIdx.x;
  int lo = t * CH, hi = lo + CH;
  if (hi > NN) hi = NN;
  if (lo > NN) lo = NN;
  int s = 0;
  for (int i = lo; i < hi; ++i) s += cnt[i];
  ps[t] = s;
  __syncthreads();
  for (int off = 1; off < 256; off <<= 1) {
    int v = (t >= off) ? ps[t - off] : 0;
    __syncthreads();
    ps[t] += v;
    __syncthreads();
  }
  int run = (t > 0) ? ps[t - 1] : 0;
  for (int i = lo; i < hi; ++i) { rp[i] = run; run += cnt[i]; }
  if (t == 255) rp[NN] = ps[255];
}

__global__ void k_scatter(const int* __restrict__ ei, const int* __restrict__ rp,
                          int* __restrict__ cur, int* __restrict__ col) {
  int i = blockIdx.x * 256 + threadIdx.x;
  if (i >= NEE) return;
  int s, d;
  if (i < NE) { s = ei[i]; d = ei[NE + i]; } else { s = i - NE; d = s; }
  int pos = atomicAdd(&cur[d], 1);
  col[rp[d] + pos] = s;
}

// ---------------- GEMM1: h1 = x @ W1  [20000,256]x[256,256], + alphas ----------------
__global__ __launch_bounds__(256) void k_gemm1(
    const float* __restrict__ x, const float* __restrict__ W1,
    const float* __restrict__ as1, const float* __restrict__ ad1,
    float* __restrict__ h1, float* __restrict__ AS1, float* __restrict__ AD1) {
  __shared__ float xsT[256][20];  // [k][row], pad 20 keeps 16B row alignment
  int c = threadIdx.x;            // output col 0..255
  int base = blockIdx.x * 16;     // 16 rows per block
  for (int i = threadIdx.x; i < 16 * 256; i += 256) {
    int r = i >> 8, k = i & 255;
    xsT[k][r] = x[(base + r) * 256 + k];
  }
  __syncthreads();
  float acc[16];
#pragma unroll
  for (int r = 0; r < 16; ++r) acc[r] = 0.f;
#pragma unroll 2
  for (int k = 0; k < 256; ++k) {
    float wv = W1[k * 256 + c];
    const float4* xr = (const float4*)&xsT[k][0];
    float4 x0 = xr[0], x1 = xr[1], x2 = xr[2], x3 = xr[3];
    acc[0] += x0.x * wv; acc[1] += x0.y * wv; acc[2] += x0.z * wv; acc[3] += x0.w * wv;
    acc[4] += x1.x * wv; acc[5] += x1.y * wv; acc[6] += x1.z * wv; acc[7] += x1.w * wv;
    acc[8] += x2.x * wv; acc[9] += x2.y * wv; acc[10] += x2.z * wv; acc[11] += x2.w * wv;
    acc[12] += x3.x * wv; acc[13] += x3.y * wv; acc[14] += x3.z * wv; acc[15] += x3.w * wv;
  }
  int head = c >> 6;
  float asv = as1[c];  // flat [head][c&63] == c
  float adv = ad1[c];
#pragma unroll
  for (int r = 0; r < 16; ++r) {
    h1[(base + r) * 256 + c] = acc[r];
    float vs = acc[r] * asv, vd = acc[r] * adv;
#pragma unroll
    for (int off = 32; off > 0; off >>= 1) {
      vs += __shfl_xor(vs, off);
      vd += __shfl_xor(vd, off);
    }
    if ((c & 63) == 0) {
      AS1[(base + r) * 4 + head] = vs;
      AD1[(base + r) * 4 + head] = vd;
    }
  }
}

// ---------------- GAT layer-1 aggregation: wave per node ----------------
__global__ __launch_bounds__(256) void k_agg1(
    const int* __restrict__ rp, const int* __restrict__ col,
    const float* __restrict__ h1, const float* __restrict__ AS1,
    const float* __restrict__ AD1, float* __restrict__ out) {
  int wave = threadIdx.x >> 6, lane = threadIdx.x & 63;
  int n = blockIdx.x * 4 + wave;
  int head = lane >> 4;
  int c4 = lane * 4;
  float adv = AD1[n * 4 + head];
  int e0 = rp[n], e1 = rp[n + 1];
  float ax = 0.f, ay = 0.f, az = 0.f, aw = 0.f, den = 0.f;
  for (int e = e0; e < e1; ++e) {
    int s = col[e];
    float ev = AS1[s * 4 + head] + adv;
    ev = ev > 0.f ? ev : NEG * ev;
    float p = __expf(ev);
    float4 hv = *(const float4*)(h1 + s * 256 + c4);
    ax += p * hv.x; ay += p * hv.y; az += p * hv.z; aw += p * hv.w;
    den += p;
  }
  float inv = 1.f / den;
  float4 o; o.x = ax * inv; o.y = ay * inv; o.z = az * inv; o.w = aw * inv;
  *(float4*)(out + n * 256 + c4) = o;
}

// ---------------- bias + ELU ----------------
__global__ void k_elu1(float* __restrict__ h, const float* __restrict__ b) {
  int i = blockIdx.x * 256 + threadIdx.x;  // NN*256 exact
  float v = h[i] + b[i & 255];
  h[i] = v > 0.f ? v : __expf(v) - 1.f;
}

__global__ void k_elu2(float* __restrict__ h, const float* __restrict__ b) {
  int i = blockIdx.x * 256 + threadIdx.x;  // NN*64 exact
  float v = h[i] + b[i & 63];
  h[i] = v > 0.f ? v : __expf(v) - 1.f;
}

// ---------------- GEMM2: h2 = h1act @ W2  [20000,256]x[256,64], + alphas ----------------
__global__ __launch_bounds__(256) void k_gemm2(
    const float* __restrict__ h1a, const float* __restrict__ W2,
    const float* __restrict__ as2, const float* __restrict__ ad2,
    float* __restrict__ h2, float* __restrict__ AS2, float* __restrict__ AD2) {
  __shared__ float xsT[256][20];
  int tid = threadIdx.x;
  int c = tid & 63, w = tid >> 6;  // wave w handles rows 4w..4w+3
  int base = blockIdx.x * 16;
  for (int i = tid; i < 16 * 256; i += 256) {
    int r = i >> 8, k = i & 255;
    xsT[k][r] = h1a[(base + r) * 256 + k];
  }
  __syncthreads();
  float acc[4] = {0.f, 0.f, 0.f, 0.f};
#pragma unroll 2
  for (int k = 0; k < 256; ++k) {
    float wv = W2[k * 64 + c];
    float4 xv = *(const float4*)&xsT[k][w * 4];
    acc[0] += xv.x * wv; acc[1] += xv.y * wv; acc[2] += xv.z * wv; acc[3] += xv.w * wv;
  }
  float asv = as2[c], adv = ad2[c];
#pragma unroll
  for (int rr = 0; rr < 4; ++rr) {
    int row = base + w * 4 + rr;
    h2[row * 64 + c] = acc[rr];
    float vs = acc[rr] * asv, vd = acc[rr] * adv;
#pragma unroll
    for (int off = 32; off > 0; off >>= 1) {
      vs += __shfl_xor(vs, off);
      vd += __shfl_xor(vd, off);
    }
    if (c == 0) { AS2[row] = vs; AD2[row] = vd; }
  }
}

// ---------------- GAT layer-2 aggregation ----------------
__global__ __launch_bounds__(256) void k_agg2(
    const int* __restrict__ rp, const int* __restrict__ col,
    const float* __restrict__ h2, const float* __restrict__ AS2,
    const float* __restrict__ AD2, float* __restrict__ out) {
  int wave = threadIdx.x >> 6, lane = threadIdx.x & 63;
  int n = blockIdx.x * 4 + wave;
  float adv = AD2[n];
  int e0 = rp[n], e1 = rp[n + 1];
  float acc = 0.f, den = 0.f;
  for (int e = e0; e < e1; ++e) {
    int s = col[e];
    float ev = AS2[s] + adv;
    ev = ev > 0.f ? ev : NEG * ev;
    float p = __expf(ev);
    acc += p * h2[s * 64 + lane];
    den += p;
  }
  out[n * 64 + lane] = acc / den;
}

// ---------------- weight prep: transpose Wp1, pad Wp2/bp2 to 88 cols ----------------
__global__ void k_prep(const float* __restrict__ Wp1, const float* __restrict__ Wp2,
                       const float* __restrict__ bp2, float* __restrict__ Wp1T,
                       float* __restrict__ Wp2p, float* __restrict__ bp2p) {
  int i = blockIdx.x * 256 + threadIdx.x;
  if (i < 128 * 64) { int r = i >> 6, cc = i & 63; Wp1T[cc * 128 + r] = Wp1[i]; }
  if (i < 64 * 88) { int t = i / 88, o = i % 88; Wp2p[i] = (o < 86) ? Wp2[t * 86 + o] : 0.f; }
  if (i < 88) bp2p[i] = (i < 86) ? bp2[i] : 0.f;
}

// ---------------- pair MLP v2: two-half z compute, LDS-backed z, no spills ----------------
#define PB 128  // pairs (threads) per block

__global__ __launch_bounds__(PB) void k_pairs(
    const int* __restrict__ pairs, const float* __restrict__ h2a,
    const float* __restrict__ Wp1T, const float* __restrict__ bp1,
    const float* __restrict__ Wp2p, const float* __restrict__ bp2p,
    float* __restrict__ out) {
  // per-thread private z storage in LDS; stride 65 -> bank=(tid+t)%32, 2-way (free)
  __shared__ float zl[PB][65];
  int tid = threadIdx.x;
  int p = blockIdx.x * PB + tid;
  bool act = p < NP;
  int pc = act ? p : 0;
  int pi = pairs[2 * pc], pj = pairs[2 * pc + 1];
  const float* rowi = h2a + pi * 64;
  const float* rowj = h2a + pj * 64;

  // layer 1: z = relu([h_i, h_j] @ Wp1 + bp1), computed as 2 halves of 32
  // (forced-sequential halves keep peak live VGPRs ~= 32 acc + 16 ck)
#pragma unroll 1
  for (int h = 0; h < 2; ++h) {
    float acc[32];
#pragma unroll
    for (int u = 0; u < 32; ++u) acc[u] = bp1[h * 32 + u];
#pragma unroll 1
    for (int kc = 0; kc < 8; ++kc) {  // 8 chunks of 16 k's over comb(128)
      const float* src = (kc < 4) ? rowi : rowj;
      int off = (kc & 3) * 16;
      float ck[16];
#pragma unroll
      for (int q = 0; q < 4; ++q) {
        float4 v = *(const float4*)(src + off + q * 4);
        ck[q * 4] = v.x; ck[q * 4 + 1] = v.y; ck[q * 4 + 2] = v.z; ck[q * 4 + 3] = v.w;
      }
      int k0 = kc * 16;
#pragma unroll
      for (int kk = 0; kk < 16; ++kk)
#pragma unroll
        for (int u = 0; u < 32; ++u)
          acc[u] += ck[kk] * Wp1T[(h * 32 + u) * 128 + k0 + kk];  // scalar (uniform) weight
    }
#pragma unroll
    for (int u = 0; u < 32; ++u) zl[tid][h * 32 + u] = fmaxf(acc[u], 0.f);
  }

  // layer 2: out = z @ Wp2 + bp2, 4 column chunks of 22 (weights padded to 88)
#pragma unroll 1
  for (int q = 0; q < 4; ++q) {
    int o0 = q * 22;
    float acc2[22];
#pragma unroll
    for (int j = 0; j < 22; ++j) acc2[j] = bp2p[o0 + j];
#pragma unroll 4
    for (int t = 0; t < 64; ++t) {
      float zt = zl[tid][t];
#pragma unroll
      for (int j = 0; j < 22; ++j)
        acc2[j] += zt * Wp2p[t * 88 + o0 + j];  // scalar (uniform) weight
    }
    if (act) {
#pragma unroll
      for (int j = 0; j < 22; ++j) {
        int o = o0 + j;
        if (o < 86) out[p * 86 + o] = acc2[j];
      }
    }
  }
}

extern "C" void kernel_launch(void* const* d_in, const int* in_sizes, int n_in,
                              void* d_out, int out_size, void* d_ws, size_t ws_size,
                              hipStream_t stream) {
  (void)in_sizes; (void)n_in; (void)out_size; (void)ws_size;
  const float* x      = (const float*)d_in[0];
  const int*   ei     = (const int*)d_in[1];
  const int*   pairs  = (const int*)d_in[2];
  const float* W1     = (const float*)d_in[3];
  const float* a_src1 = (const float*)d_in[4];
  const float* a_dst1 = (const float*)d_in[5];
  const float* b1     = (const float*)d_in[6];
  const float* W2     = (const float*)d_in[7];
  const float* a_src2 = (const float*)d_in[8];
  const float* a_dst2 = (const float*)d_in[9];
  const float* b2     = (const float*)d_in[10];
  const float* Wp1    = (const float*)d_in[11];
  const float* bp1    = (const float*)d_in[12];
  const float* Wp2    = (const float*)d_in[13];
  const float* bp2    = (const float*)d_in[14];
  float* out = (float*)d_out;

  char* w = (char*)d_ws;
  auto alloc = [&](size_t bytes) -> void* {
    void* pp = (void*)w;
    w += (bytes + 255) & ~(size_t)255;
    return pp;
  };
  float* h1    = (float*)alloc((size_t)NN * 256 * 4);
  float* AS1   = (float*)alloc((size_t)NN * 4 * 4);
  float* AD1   = (float*)alloc((size_t)NN * 4 * 4);
  float* h1agg = (float*)alloc((size_t)NN * 256 * 4);
  float* h2    = (float*)alloc((size_t)NN * 64 * 4);
  float* AS2   = (float*)alloc((size_t)NN * 4);
  float* AD2   = (float*)alloc((size_t)NN * 4);
  float* h2agg = (float*)alloc((size_t)NN * 64 * 4);
  float* Wp1T  = (float*)alloc(64 * 128 * 4);
  float* Wp2p  = (float*)alloc(64 * 88 * 4);
  float* bp2p  = (float*)alloc(88 * 4);
  int*   rp    = (int*)alloc((size_t)(NN + 1) * 4);
  int*   cnt   = (int*)alloc((size_t)NN * 4);
  int*   cur   = (int*)alloc((size_t)NN * 4);
  int*   col   = (int*)alloc((size_t)NEE * 4);

  hipMemsetAsync(cnt, 0, (size_t)NN * 4, stream);
  hipMemsetAsync(cur, 0, (size_t)NN * 4, stream);

  const int EB = (NEE + 255) / 256;  // 2579
  k_hist<<<EB, 256, 0, stream>>>(ei, cnt);
  k_scan<<<1, 256, 0, stream>>>(cnt, rp);
  k_scatter<<<EB, 256, 0, stream>>>(ei, rp, cur, col);
  k_prep<<<32, 256, 0, stream>>>(Wp1, Wp2, bp2, Wp1T, Wp2p, bp2p);

  k_gemm1<<<NN / 16, 256, 0, stream>>>(x, W1, a_src1, a_dst1, h1, AS1, AD1);
  k_agg1<<<NN / 4, 256, 0, stream>>>(rp, col, h1, AS1, AD1, h1agg);
  k_elu1<<<NN * 256 / 256, 256, 0, stream>>>(h1agg, b1);

  k_gemm2<<<NN / 16, 256, 0, stream>>>(h1agg, W2, a_src2, a_dst2, h2, AS2, AD2);
  k_agg2<<<NN / 4, 256, 0, stream>>>(rp, col, h2, AS2, AD2, h2agg);
  k_elu2<<<NN * 64 / 256, 256, 0, stream>>>(h2agg, b2);

  k_pairs<<<(NP + PB - 1) / PB, PB, 0, stream>>>(pairs, h2agg, Wp1T, bp1, Wp2p, bp2p, out);
}

// Round 3
// 745.626 us; speedup vs baseline: 1.0044x; 1.0044x over previous
//
#include <hip/hip_runtime.h>

#define NN 20000      // nodes
#define NE 640000     // edges (without self loops)
#define NEE 660000    // edges + self loops
#define NP 200000     // drug pairs
#define NEG 0.2f      // leaky relu slope

// ---------------- CSR build ----------------
__global__ void k_hist(const int* __restrict__ ei, int* __restrict__ cnt) {
  int i = blockIdx.x * 256 + threadIdx.x;
  if (i >= NEE) return;
  int d = (i < NE) ? ei[NE + i] : (i - NE);
  atomicAdd(&cnt[d], 1);
}

__global__ void k_scan(const int* __restrict__ cnt, int* __restrict__ rp) {
  __shared__ int ps[256];
  const int CH = 79;  // 79*256 = 20224 >= 20000
  int t = threadIdx.x;
  int lo = t * CH, hi = lo + CH;
  if (hi > NN) hi = NN;
  if (lo > NN) lo = NN;
  int s = 0;
  for (int i = lo; i < hi; ++i) s += cnt[i];
  ps[t] = s;
  __syncthreads();
  for (int off = 1; off < 256; off <<= 1) {
    int v = (t >= off) ? ps[t - off] : 0;
    __syncthreads();
    ps[t] += v;
    __syncthreads();
  }
  int run = (t > 0) ? ps[t - 1] : 0;
  for (int i = lo; i < hi; ++i) { rp[i] = run; run += cnt[i]; }
  if (t == 255) rp[NN] = ps[255];
}

__global__ void k_scatter(const int* __restrict__ ei, const int* __restrict__ rp,
                          int* __restrict__ cur, int* __restrict__ col) {
  int i = blockIdx.x * 256 + threadIdx.x;
  if (i >= NEE) return;
  int s, d;
  if (i < NE) { s = ei[i]; d = ei[NE + i]; } else { s = i - NE; d = s; }
  int pos = atomicAdd(&cur[d], 1);
  col[rp[d] + pos] = s;
}

// ---------------- GEMM1: h1 = x @ W1  [20000,256]x[256,256], + alphas ----------------
__global__ __launch_bounds__(256) void k_gemm1(
    const float* __restrict__ x, const float* __restrict__ W1,
    const float* __restrict__ as1, const float* __restrict__ ad1,
    float* __restrict__ h1, float* __restrict__ AS1, float* __restrict__ AD1) {
  __shared__ float xsT[256][20];  // [k][row], pad 20 keeps 16B row alignment
  int c = threadIdx.x;            // output col 0..255
  int base = blockIdx.x * 16;     // 16 rows per block
  for (int i = threadIdx.x; i < 16 * 256; i += 256) {
    int r = i >> 8, k = i & 255;
    xsT[k][r] = x[(base + r) * 256 + k];
  }
  __syncthreads();
  float acc[16];
#pragma unroll
  for (int r = 0; r < 16; ++r) acc[r] = 0.f;
#pragma unroll 2
  for (int k = 0; k < 256; ++k) {
    float wv = W1[k * 256 + c];
    const float4* xr = (const float4*)&xsT[k][0];
    float4 x0 = xr[0], x1 = xr[1], x2 = xr[2], x3 = xr[3];
    acc[0] += x0.x * wv; acc[1] += x0.y * wv; acc[2] += x0.z * wv; acc[3] += x0.w * wv;
    acc[4] += x1.x * wv; acc[5] += x1.y * wv; acc[6] += x1.z * wv; acc[7] += x1.w * wv;
    acc[8] += x2.x * wv; acc[9] += x2.y * wv; acc[10] += x2.z * wv; acc[11] += x2.w * wv;
    acc[12] += x3.x * wv; acc[13] += x3.y * wv; acc[14] += x3.z * wv; acc[15] += x3.w * wv;
  }
  int head = c >> 6;
  float asv = as1[c];  // flat [head][c&63] == c
  float adv = ad1[c];
#pragma unroll
  for (int r = 0; r < 16; ++r) {
    h1[(base + r) * 256 + c] = acc[r];
    float vs = acc[r] * asv, vd = acc[r] * adv;
#pragma unroll
    for (int off = 32; off > 0; off >>= 1) {
      vs += __shfl_xor(vs, off);
      vd += __shfl_xor(vd, off);
    }
    if ((c & 63) == 0) {
      AS1[(base + r) * 4 + head] = vs;
      AD1[(base + r) * 4 + head] = vd;
    }
  }
}

// ---------------- GAT layer-1 aggregation: wave per node ----------------
__global__ __launch_bounds__(256) void k_agg1(
    const int* __restrict__ rp, const int* __restrict__ col,
    const float* __restrict__ h1, const float* __restrict__ AS1,
    const float* __restrict__ AD1, float* __restrict__ out) {
  int wave = threadIdx.x >> 6, lane = threadIdx.x & 63;
  int n = blockIdx.x * 4 + wave;
  int head = lane >> 4;
  int c4 = lane * 4;
  float adv = AD1[n * 4 + head];
  int e0 = rp[n], e1 = rp[n + 1];
  float ax = 0.f, ay = 0.f, az = 0.f, aw = 0.f, den = 0.f;
  for (int e = e0; e < e1; ++e) {
    int s = col[e];
    float ev = AS1[s * 4 + head] + adv;
    ev = ev > 0.f ? ev : NEG * ev;
    float p = __expf(ev);
    float4 hv = *(const float4*)(h1 + s * 256 + c4);
    ax += p * hv.x; ay += p * hv.y; az += p * hv.z; aw += p * hv.w;
    den += p;
  }
  float inv = 1.f / den;
  float4 o; o.x = ax * inv; o.y = ay * inv; o.z = az * inv; o.w = aw * inv;
  *(float4*)(out + n * 256 + c4) = o;
}

// ---------------- bias + ELU ----------------
__global__ void k_elu1(float* __restrict__ h, const float* __restrict__ b) {
  int i = blockIdx.x * 256 + threadIdx.x;  // NN*256 exact
  float v = h[i] + b[i & 255];
  h[i] = v > 0.f ? v : __expf(v) - 1.f;
}

__global__ void k_elu2(float* __restrict__ h, const float* __restrict__ b) {
  int i = blockIdx.x * 256 + threadIdx.x;  // NN*64 exact
  float v = h[i] + b[i & 63];
  h[i] = v > 0.f ? v : __expf(v) - 1.f;
}

// ---------------- GEMM2: h2 = h1act @ W2  [20000,256]x[256,64], + alphas ----------------
__global__ __launch_bounds__(256) void k_gemm2(
    const float* __restrict__ h1a, const float* __restrict__ W2,
    const float* __restrict__ as2, const float* __restrict__ ad2,
    float* __restrict__ h2, float* __restrict__ AS2, float* __restrict__ AD2) {
  __shared__ float xsT[256][20];
  int tid = threadIdx.x;
  int c = tid & 63, w = tid >> 6;  // wave w handles rows 4w..4w+3
  int base = blockIdx.x * 16;
  for (int i = tid; i < 16 * 256; i += 256) {
    int r = i >> 8, k = i & 255;
    xsT[k][r] = h1a[(base + r) * 256 + k];
  }
  __syncthreads();
  float acc[4] = {0.f, 0.f, 0.f, 0.f};
#pragma unroll 2
  for (int k = 0; k < 256; ++k) {
    float wv = W2[k * 64 + c];
    float4 xv = *(const float4*)&xsT[k][w * 4];
    acc[0] += xv.x * wv; acc[1] += xv.y * wv; acc[2] += xv.z * wv; acc[3] += xv.w * wv;
  }
  float asv = as2[c], adv = ad2[c];
#pragma unroll
  for (int rr = 0; rr < 4; ++rr) {
    int row = base + w * 4 + rr;
    h2[row * 64 + c] = acc[rr];
    float vs = acc[rr] * asv, vd = acc[rr] * adv;
#pragma unroll
    for (int off = 32; off > 0; off >>= 1) {
      vs += __shfl_xor(vs, off);
      vd += __shfl_xor(vd, off);
    }
    if (c == 0) { AS2[row] = vs; AD2[row] = vd; }
  }
}

// ---------------- GAT layer-2 aggregation ----------------
__global__ __launch_bounds__(256) void k_agg2(
    const int* __restrict__ rp, const int* __restrict__ col,
    const float* __restrict__ h2, const float* __restrict__ AS2,
    const float* __restrict__ AD2, float* __restrict__ out) {
  int wave = threadIdx.x >> 6, lane = threadIdx.x & 63;
  int n = blockIdx.x * 4 + wave;
  float adv = AD2[n];
  int e0 = rp[n], e1 = rp[n + 1];
  float acc = 0.f, den = 0.f;
  for (int e = e0; e < e1; ++e) {
    int s = col[e];
    float ev = AS2[s] + adv;
    ev = ev > 0.f ? ev : NEG * ev;
    float p = __expf(ev);
    acc += p * h2[s * 64 + lane];
    den += p;
  }
  out[n * 64 + lane] = acc / den;
}

// ---------------- weight prep: transpose Wp1, pad Wp2/bp2 to 88 cols ----------------
__global__ void k_prep(const float* __restrict__ Wp1, const float* __restrict__ Wp2,
                       const float* __restrict__ bp2, float* __restrict__ Wp1T,
                       float* __restrict__ Wp2p, float* __restrict__ bp2p) {
  int i = blockIdx.x * 256 + threadIdx.x;
  if (i < 128 * 64) { int r = i >> 6, cc = i & 63; Wp1T[cc * 128 + r] = Wp1[i]; }
  if (i < 64 * 88) { int t = i / 88, o = i % 88; Wp2p[i] = (o < 86) ? Wp2[t * 86 + o] : 0.f; }
  if (i < 88) bp2p[i] = (i < 86) ? bp2[i] : 0.f;
}

// ---------------- pair MLP v2: two-half z compute, LDS-backed z, no spills ----------------
#define PB 128  // pairs (threads) per block

__global__ __launch_bounds__(PB) void k_pairs(
    const int* __restrict__ pairs, const float* __restrict__ h2a,
    const float* __restrict__ Wp1T, const float* __restrict__ bp1,
    const float* __restrict__ Wp2p, const float* __restrict__ bp2p,
    float* __restrict__ out) {
  // per-thread private z storage in LDS; stride 65 -> bank=(tid+t)%32, 2-way (free)
  __shared__ float zl[PB][65];
  int tid = threadIdx.x;
  int p = blockIdx.x * PB + tid;
  bool act = p < NP;
  int pc = act ? p : 0;
  int pi = pairs[2 * pc], pj = pairs[2 * pc + 1];
  const float* rowi = h2a + pi * 64;
  const float* rowj = h2a + pj * 64;

  // layer 1: z = relu([h_i, h_j] @ Wp1 + bp1), computed as 2 halves of 32
  // (forced-sequential halves keep peak live VGPRs ~= 32 acc + 16 ck)
#pragma unroll 1
  for (int h = 0; h < 2; ++h) {
    float acc[32];
#pragma unroll
    for (int u = 0; u < 32; ++u) acc[u] = bp1[h * 32 + u];
#pragma unroll 1
    for (int kc = 0; kc < 8; ++kc) {  // 8 chunks of 16 k's over comb(128)
      const float* src = (kc < 4) ? rowi : rowj;
      int off = (kc & 3) * 16;
      float ck[16];
#pragma unroll
      for (int q = 0; q < 4; ++q) {
        float4 v = *(const float4*)(src + off + q * 4);
        ck[q * 4] = v.x; ck[q * 4 + 1] = v.y; ck[q * 4 + 2] = v.z; ck[q * 4 + 3] = v.w;
      }
      int k0 = kc * 16;
#pragma unroll
      for (int kk = 0; kk < 16; ++kk)
#pragma unroll
        for (int u = 0; u < 32; ++u)
          acc[u] += ck[kk] * Wp1T[(h * 32 + u) * 128 + k0 + kk];  // scalar (uniform) weight
    }
#pragma unroll
    for (int u = 0; u < 32; ++u) zl[tid][h * 32 + u] = fmaxf(acc[u], 0.f);
  }

  // layer 2: out = z @ Wp2 + bp2, 4 column chunks of 22 (weights padded to 88)
#pragma unroll 1
  for (int q = 0; q < 4; ++q) {
    int o0 = q * 22;
    float acc2[22];
#pragma unroll
    for (int j = 0; j < 22; ++j) acc2[j] = bp2p[o0 + j];
#pragma unroll 4
    for (int t = 0; t < 64; ++t) {
      float zt = zl[tid][t];
#pragma unroll
      for (int j = 0; j < 22; ++j)
        acc2[j] += zt * Wp2p[t * 88 + o0 + j];  // scalar (uniform) weight
    }
    if (act) {
#pragma unroll
      for (int j = 0; j < 22; ++j) {
        int o = o0 + j;
        if (o < 86) out[p * 86 + o] = acc2[j];
      }
    }
  }
}

extern "C" void kernel_launch(void* const* d_in, const int* in_sizes, int n_in,
                              void* d_out, int out_size, void* d_ws, size_t ws_size,
                              hipStream_t stream) {
  (void)in_sizes; (void)n_in; (void)out_size; (void)ws_size;
  const float* x      = (const float*)d_in[0];
  const int*   ei     = (const int*)d_in[1];
  const int*   pairs  = (const int*)d_in[2];
  const float* W1     = (const float*)d_in[3];
  const float* a_src1 = (const float*)d_in[4];
  const float* a_dst1 = (const float*)d_in[5];
  const float* b1     = (const float*)d_in[6];
  const float* W2     = (const float*)d_in[7];
  const float* a_src2 = (const float*)d_in[8];
  const float* a_dst2 = (const float*)d_in[9];
  const float* b2     = (const float*)d_in[10];
  const float* Wp1    = (const float*)d_in[11];
  const float* bp1    = (const float*)d_in[12];
  const float* Wp2    = (const float*)d_in[13];
  const float* bp2    = (const float*)d_in[14];
  float* out = (float*)d_out;

  char* w = (char*)d_ws;
  auto alloc = [&](size_t bytes) -> void* {
    void* pp = (void*)w;
    w += (bytes + 255) & ~(size_t)255;
    return pp;
  };
  float* h1    = (float*)alloc((size_t)NN * 256 * 4);
  float* AS1   = (float*)alloc((size_t)NN * 4 * 4);
  float* AD1   = (float*)alloc((size_t)NN * 4 * 4);
  float* h1agg = (float*)alloc((size_t)NN * 256 * 4);
  float* h2    = (float*)alloc((size_t)NN * 64 * 4);
  float* AS2   = (float*)alloc((size_t)NN * 4);
  float* AD2   = (float*)alloc((size_t)NN * 4);
  float* h2agg = (float*)alloc((size_t)NN * 64 * 4);
  float* Wp1T  = (float*)alloc(64 * 128 * 4);
  float* Wp2p  = (float*)alloc(64 * 88 * 4);
  float* bp2p  = (float*)alloc(88 * 4);
  int*   rp    = (int*)alloc((size_t)(NN + 1) * 4);
  int*   cnt   = (int*)alloc((size_t)NN * 4);
  int*   cur   = (int*)alloc((size_t)NN * 4);
  int*   col   = (int*)alloc((size_t)NEE * 4);

  hipMemsetAsync(cnt, 0, (size_t)NN * 4, stream);
  hipMemsetAsync(cur, 0, (size_t)NN * 4, stream);

  const int EB = (NEE + 255) / 256;  // 2579
  k_hist<<<EB, 256, 0, stream>>>(ei, cnt);
  k_scan<<<1, 256, 0, stream>>>(cnt, rp);
  k_scatter<<<EB, 256, 0, stream>>>(ei, rp, cur, col);
  k_prep<<<32, 256, 0, stream>>>(Wp1, Wp2, bp2, Wp1T, Wp2p, bp2p);

  k_gemm1<<<NN / 16, 256, 0, stream>>>(x, W1, a_src1, a_dst1, h1, AS1, AD1);
  k_agg1<<<NN / 4, 256, 0, stream>>>(rp, col, h1, AS1, AD1, h1agg);
  k_elu1<<<NN * 256 / 256, 256, 0, stream>>>(h1agg, b1);

  k_gemm2<<<NN / 16, 256, 0, stream>>>(h1agg, W2, a_src2, a_dst2, h2, AS2, AD2);
  k_agg2<<<NN / 4, 256, 0, stream>>>(rp, col, h2, AS2, AD2, h2agg);
  k_elu2<<<NN * 64 / 256, 256, 0, stream>>>(h2agg, b2);

  k_pairs<<<(NP + PB - 1) / PB, PB, 0, stream>>>(pairs, h2agg, Wp1T, bp1, Wp2p, bp2p, out);
}

// Round 4
// 523.720 us; speedup vs baseline: 1.4300x; 1.4237x over previous
//
#include <hip/hip_runtime.h>

#define NN 20000      // nodes
#define NE 640000     // edges (without self loops)
#define NEE 660000    // edges + self loops
#define NP 200000     // drug pairs
#define NEG 0.2f      // leaky relu slope

// ---------------- CSR build ----------------
__global__ void k_hist(const int* __restrict__ ei, int* __restrict__ cnt) {
  int i = blockIdx.x * 256 + threadIdx.x;
  if (i >= NEE) return;
  int d = (i < NE) ? ei[NE + i] : (i - NE);
  atomicAdd(&cnt[d], 1);
}

__global__ void k_scan(const int* __restrict__ cnt, int* __restrict__ rp) {
  __shared__ int ps[256];
  const int CH = 79;  // 79*256 = 20224 >= 20000
  int t = threadIdx.x;
  int lo = t * CH, hi = lo + CH;
  if (hi > NN) hi = NN;
  if (lo > NN) lo = NN;
  int s = 0;
  for (int i = lo; i < hi; ++i) s += cnt[i];
  ps[t] = s;
  __syncthreads();
  for (int off = 1; off < 256; off <<= 1) {
    int v = (t >= off) ? ps[t - off] : 0;
    __syncthreads();
    ps[t] += v;
    __syncthreads();
  }
  int run = (t > 0) ? ps[t - 1] : 0;
  for (int i = lo; i < hi; ++i) { rp[i] = run; run += cnt[i]; }
  if (t == 255) rp[NN] = ps[255];
}

__global__ void k_scatter(const int* __restrict__ ei, const int* __restrict__ rp,
                          int* __restrict__ cur, int* __restrict__ col) {
  int i = blockIdx.x * 256 + threadIdx.x;
  if (i >= NEE) return;
  int s, d;
  if (i < NE) { s = ei[i]; d = ei[NE + i]; } else { s = i - NE; d = s; }
  int pos = atomicAdd(&cur[d], 1);
  col[rp[d] + pos] = s;
}

// ---------------- GEMM1: h1 = x @ W1  [20000,256]x[256,256], + alphas ----------------
__global__ __launch_bounds__(256) void k_gemm1(
    const float* __restrict__ x, const float* __restrict__ W1,
    const float* __restrict__ as1, const float* __restrict__ ad1,
    float* __restrict__ h1, float* __restrict__ AS1, float* __restrict__ AD1) {
  __shared__ float xsT[256][20];  // [k][row], pad 20 keeps 16B row alignment
  int c = threadIdx.x;            // output col 0..255
  int base = blockIdx.x * 16;     // 16 rows per block
  for (int i = threadIdx.x; i < 16 * 256; i += 256) {
    int r = i >> 8, k = i & 255;
    xsT[k][r] = x[(base + r) * 256 + k];
  }
  __syncthreads();
  float acc[16];
#pragma unroll
  for (int r = 0; r < 16; ++r) acc[r] = 0.f;
#pragma unroll 2
  for (int k = 0; k < 256; ++k) {
    float wv = W1[k * 256 + c];
    const float4* xr = (const float4*)&xsT[k][0];
    float4 x0 = xr[0], x1 = xr[1], x2 = xr[2], x3 = xr[3];
    acc[0] += x0.x * wv; acc[1] += x0.y * wv; acc[2] += x0.z * wv; acc[3] += x0.w * wv;
    acc[4] += x1.x * wv; acc[5] += x1.y * wv; acc[6] += x1.z * wv; acc[7] += x1.w * wv;
    acc[8] += x2.x * wv; acc[9] += x2.y * wv; acc[10] += x2.z * wv; acc[11] += x2.w * wv;
    acc[12] += x3.x * wv; acc[13] += x3.y * wv; acc[14] += x3.z * wv; acc[15] += x3.w * wv;
  }
  int head = c >> 6;
  float asv = as1[c];  // flat [head][c&63] == c
  float adv = ad1[c];
#pragma unroll
  for (int r = 0; r < 16; ++r) {
    h1[(base + r) * 256 + c] = acc[r];
    float vs = acc[r] * asv, vd = acc[r] * adv;
#pragma unroll
    for (int off = 32; off > 0; off >>= 1) {
      vs += __shfl_xor(vs, off);
      vd += __shfl_xor(vd, off);
    }
    if ((c & 63) == 0) {
      AS1[(base + r) * 4 + head] = vs;
      AD1[(base + r) * 4 + head] = vd;
    }
  }
}

// ---------------- GAT layer-1 aggregation: wave per node ----------------
__global__ __launch_bounds__(256) void k_agg1(
    const int* __restrict__ rp, const int* __restrict__ col,
    const float* __restrict__ h1, const float* __restrict__ AS1,
    const float* __restrict__ AD1, float* __restrict__ out) {
  int wave = threadIdx.x >> 6, lane = threadIdx.x & 63;
  int n = blockIdx.x * 4 + wave;
  int head = lane >> 4;
  int c4 = lane * 4;
  float adv = AD1[n * 4 + head];
  int e0 = rp[n], e1 = rp[n + 1];
  float ax = 0.f, ay = 0.f, az = 0.f, aw = 0.f, den = 0.f;
  for (int e = e0; e < e1; ++e) {
    int s = col[e];
    float ev = AS1[s * 4 + head] + adv;
    ev = ev > 0.f ? ev : NEG * ev;
    float p = __expf(ev);
    float4 hv = *(const float4*)(h1 + s * 256 + c4);
    ax += p * hv.x; ay += p * hv.y; az += p * hv.z; aw += p * hv.w;
    den += p;
  }
  float inv = 1.f / den;
  float4 o; o.x = ax * inv; o.y = ay * inv; o.z = az * inv; o.w = aw * inv;
  *(float4*)(out + n * 256 + c4) = o;
}

// ---------------- bias + ELU ----------------
__global__ void k_elu1(float* __restrict__ h, const float* __restrict__ b) {
  int i = blockIdx.x * 256 + threadIdx.x;  // NN*256 exact
  float v = h[i] + b[i & 255];
  h[i] = v > 0.f ? v : __expf(v) - 1.f;
}

__global__ void k_elu2(float* __restrict__ h, const float* __restrict__ b) {
  int i = blockIdx.x * 256 + threadIdx.x;  // NN*64 exact
  float v = h[i] + b[i & 63];
  h[i] = v > 0.f ? v : __expf(v) - 1.f;
}

// ---------------- GEMM2: h2 = h1act @ W2  [20000,256]x[256,64], + alphas ----------------
__global__ __launch_bounds__(256) void k_gemm2(
    const float* __restrict__ h1a, const float* __restrict__ W2,
    const float* __restrict__ as2, const float* __restrict__ ad2,
    float* __restrict__ h2, float* __restrict__ AS2, float* __restrict__ AD2) {
  __shared__ float xsT[256][20];
  int tid = threadIdx.x;
  int c = tid & 63, w = tid >> 6;  // wave w handles rows 4w..4w+3
  int base = blockIdx.x * 16;
  for (int i = tid; i < 16 * 256; i += 256) {
    int r = i >> 8, k = i & 255;
    xsT[k][r] = h1a[(base + r) * 256 + k];
  }
  __syncthreads();
  float acc[4] = {0.f, 0.f, 0.f, 0.f};
#pragma unroll 2
  for (int k = 0; k < 256; ++k) {
    float wv = W2[k * 64 + c];
    float4 xv = *(const float4*)&xsT[k][w * 4];
    acc[0] += xv.x * wv; acc[1] += xv.y * wv; acc[2] += xv.z * wv; acc[3] += xv.w * wv;
  }
  float asv = as2[c], adv = ad2[c];
#pragma unroll
  for (int rr = 0; rr < 4; ++rr) {
    int row = base + w * 4 + rr;
    h2[row * 64 + c] = acc[rr];
    float vs = acc[rr] * asv, vd = acc[rr] * adv;
#pragma unroll
    for (int off = 32; off > 0; off >>= 1) {
      vs += __shfl_xor(vs, off);
      vd += __shfl_xor(vd, off);
    }
    if (c == 0) { AS2[row] = vs; AD2[row] = vd; }
  }
}

// ---------------- GAT layer-2 aggregation ----------------
__global__ __launch_bounds__(256) void k_agg2(
    const int* __restrict__ rp, const int* __restrict__ col,
    const float* __restrict__ h2, const float* __restrict__ AS2,
    const float* __restrict__ AD2, float* __restrict__ out) {
  int wave = threadIdx.x >> 6, lane = threadIdx.x & 63;
  int n = blockIdx.x * 4 + wave;
  float adv = AD2[n];
  int e0 = rp[n], e1 = rp[n + 1];
  float acc = 0.f, den = 0.f;
  for (int e = e0; e < e1; ++e) {
    int s = col[e];
    float ev = AS2[s] + adv;
    ev = ev > 0.f ? ev : NEG * ev;
    float p = __expf(ev);
    acc += p * h2[s * 64 + lane];
    den += p;
  }
  out[n * 64 + lane] = acc / den;
}

// ---------------- pair MLP v3: all-register z, bounded live set, SGPR weights ----------------
// One thread per pair. z[64] lives in VGPRs the whole kernel; comb is staged
// 32 floats at a time (8x float4, issued together so latency amortizes);
// layer 2 runs as two 43-column chunks (43+43=86, no padding needed) with
// stores only in two adjacent phases so each output cache line flushes once.
// Weights are read at thread-uniform addresses with the innermost
// (compile-time) index walking consecutive floats -> s_load_dwordxN batches.
// Peak live VGPRs ~= 64(z) + 43(acc) + addr ~ 112; launch_bounds(256,2)
// gives the allocator a 256-VGPR budget so it cannot repeat round-1's
// 56-VGPR spill disaster.
__global__ __launch_bounds__(256, 2) void k_pairs(
    const int* __restrict__ pairs, const float* __restrict__ h2a,
    const float* __restrict__ Wp1, const float* __restrict__ bp1,
    const float* __restrict__ Wp2, const float* __restrict__ bp2,
    float* __restrict__ out) {
  int p = blockIdx.x * 256 + threadIdx.x;
  bool act = p < NP;
  int pc = act ? p : 0;
  int pi = pairs[2 * pc], pj = pairs[2 * pc + 1];
  const float* rowi = h2a + pi * 64;
  const float* rowj = h2a + pj * 64;

  float z[64];
#pragma unroll
  for (int u = 0; u < 64; ++u) z[u] = bp1[u];

  // layer 1: z += comb @ Wp1; comb = [rowi(64), rowj(64)] processed in 4 groups of 32 k
#pragma unroll 1
  for (int g = 0; g < 4; ++g) {
    const float* src = (g < 2) ? rowi : rowj;
    int off = (g & 1) * 32;
    float ck[32];
#pragma unroll
    for (int q = 0; q < 8; ++q) {
      float4 v = *(const float4*)(src + off + q * 4);
      ck[q * 4] = v.x; ck[q * 4 + 1] = v.y; ck[q * 4 + 2] = v.z; ck[q * 4 + 3] = v.w;
    }
    int k0 = g * 32;
#pragma unroll
    for (int kk = 0; kk < 32; ++kk)
#pragma unroll
      for (int u = 0; u < 64; ++u)
        z[u] += ck[kk] * Wp1[(k0 + kk) * 64 + u];  // uniform addr, u consecutive -> s_load batches
  }
#pragma unroll
  for (int u = 0; u < 64; ++u) z[u] = fmaxf(z[u], 0.f);

  // layer 2: out = z @ Wp2 + bp2, two chunks of 43 columns
#pragma unroll 1
  for (int cch = 0; cch < 2; ++cch) {
    int o0 = cch * 43;
    float acc[43];
#pragma unroll
    for (int j = 0; j < 43; ++j) acc[j] = bp2[o0 + j];
#pragma unroll 2
    for (int t = 0; t < 64; ++t) {
      float zt = z[t];
#pragma unroll
      for (int j = 0; j < 43; ++j)
        acc[j] += zt * Wp2[t * 86 + o0 + j];  // uniform addr, j consecutive -> s_load batches
    }
    if (act) {
#pragma unroll
      for (int j = 0; j < 43; ++j) out[p * 86 + o0 + j] = acc[j];
    }
  }
}

extern "C" void kernel_launch(void* const* d_in, const int* in_sizes, int n_in,
                              void* d_out, int out_size, void* d_ws, size_t ws_size,
                              hipStream_t stream) {
  (void)in_sizes; (void)n_in; (void)out_size; (void)ws_size;
  const float* x      = (const float*)d_in[0];
  const int*   ei     = (const int*)d_in[1];
  const int*   pairs  = (const int*)d_in[2];
  const float* W1     = (const float*)d_in[3];
  const float* a_src1 = (const float*)d_in[4];
  const float* a_dst1 = (const float*)d_in[5];
  const float* b1     = (const float*)d_in[6];
  const float* W2     = (const float*)d_in[7];
  const float* a_src2 = (const float*)d_in[8];
  const float* a_dst2 = (const float*)d_in[9];
  const float* b2     = (const float*)d_in[10];
  const float* Wp1    = (const float*)d_in[11];
  const float* bp1    = (const float*)d_in[12];
  const float* Wp2    = (const float*)d_in[13];
  const float* bp2    = (const float*)d_in[14];
  float* out = (float*)d_out;

  char* w = (char*)d_ws;
  auto alloc = [&](size_t bytes) -> void* {
    void* pp = (void*)w;
    w += (bytes + 255) & ~(size_t)255;
    return pp;
  };
  float* h1    = (float*)alloc((size_t)NN * 256 * 4);
  float* AS1   = (float*)alloc((size_t)NN * 4 * 4);
  float* AD1   = (float*)alloc((size_t)NN * 4 * 4);
  float* h1agg = (float*)alloc((size_t)NN * 256 * 4);
  float* h2    = (float*)alloc((size_t)NN * 64 * 4);
  float* AS2   = (float*)alloc((size_t)NN * 4);
  float* AD2   = (float*)alloc((size_t)NN * 4);
  float* h2agg = (float*)alloc((size_t)NN * 64 * 4);
  int*   rp    = (int*)alloc((size_t)(NN + 1) * 4);
  int*   cnt   = (int*)alloc((size_t)NN * 4);
  int*   cur   = (int*)alloc((size_t)NN * 4);
  int*   col   = (int*)alloc((size_t)NEE * 4);

  hipMemsetAsync(cnt, 0, (size_t)NN * 4, stream);
  hipMemsetAsync(cur, 0, (size_t)NN * 4, stream);

  const int EB = (NEE + 255) / 256;  // 2579
  k_hist<<<EB, 256, 0, stream>>>(ei, cnt);
  k_scan<<<1, 256, 0, stream>>>(cnt, rp);
  k_scatter<<<EB, 256, 0, stream>>>(ei, rp, cur, col);

  k_gemm1<<<NN / 16, 256, 0, stream>>>(x, W1, a_src1, a_dst1, h1, AS1, AD1);
  k_agg1<<<NN / 4, 256, 0, stream>>>(rp, col, h1, AS1, AD1, h1agg);
  k_elu1<<<NN * 256 / 256, 256, 0, stream>>>(h1agg, b1);

  k_gemm2<<<NN / 16, 256, 0, stream>>>(h1agg, W2, a_src2, a_dst2, h2, AS2, AD2);
  k_agg2<<<NN / 4, 256, 0, stream>>>(rp, col, h2, AS2, AD2, h2agg);
  k_elu2<<<NN * 64 / 256, 256, 0, stream>>>(h2agg, b2);

  k_pairs<<<(NP + 255) / 256, 256, 0, stream>>>(pairs, h2agg, Wp1, bp1, Wp2, bp2, out);
}

// Round 5
// 513.159 us; speedup vs baseline: 1.4595x; 1.0206x over previous
//
#include <hip/hip_runtime.h>

#define NN 20000      // nodes
#define NE 640000     // edges (without self loops)
#define NEE 660000    // edges + self loops
#define NP 200000     // drug pairs
#define NEG 0.2f      // leaky relu slope

// ---------------- CSR build ----------------
__global__ void k_hist(const int* __restrict__ ei, int* __restrict__ cnt) {
  int i = blockIdx.x * 256 + threadIdx.x;
  if (i >= NEE) return;
  int d = (i < NE) ? ei[NE + i] : (i - NE);
  atomicAdd(&cnt[d], 1);
}

__global__ void k_scan(const int* __restrict__ cnt, int* __restrict__ rp) {
  __shared__ int ps[256];
  const int CH = 79;  // 79*256 = 20224 >= 20000
  int t = threadIdx.x;
  int lo = t * CH, hi = lo + CH;
  if (hi > NN) hi = NN;
  if (lo > NN) lo = NN;
  int s = 0;
  for (int i = lo; i < hi; ++i) s += cnt[i];
  ps[t] = s;
  __syncthreads();
  for (int off = 1; off < 256; off <<= 1) {
    int v = (t >= off) ? ps[t - off] : 0;
    __syncthreads();
    ps[t] += v;
    __syncthreads();
  }
  int run = (t > 0) ? ps[t - 1] : 0;
  for (int i = lo; i < hi; ++i) { rp[i] = run; run += cnt[i]; }
  if (t == 255) rp[NN] = ps[255];
}

__global__ void k_scatter(const int* __restrict__ ei, const int* __restrict__ rp,
                          int* __restrict__ cur, int* __restrict__ col) {
  int i = blockIdx.x * 256 + threadIdx.x;
  if (i >= NEE) return;
  int s, d;
  if (i < NE) { s = ei[i]; d = ei[NE + i]; } else { s = i - NE; d = s; }
  int pos = atomicAdd(&cur[d], 1);
  col[rp[d] + pos] = s;
}

// ---------------- GEMM1: h1 = x @ W1  [20000,256]x[256,256], + alphas ----------------
__global__ __launch_bounds__(256) void k_gemm1(
    const float* __restrict__ x, const float* __restrict__ W1,
    const float* __restrict__ as1, const float* __restrict__ ad1,
    float* __restrict__ h1, float* __restrict__ AS1, float* __restrict__ AD1) {
  __shared__ float xsT[256][20];  // [k][row], pad 20 keeps 16B row alignment
  int c = threadIdx.x;            // output col 0..255
  int base = blockIdx.x * 16;     // 16 rows per block
  for (int i = threadIdx.x; i < 16 * 256; i += 256) {
    int r = i >> 8, k = i & 255;
    xsT[k][r] = x[(base + r) * 256 + k];
  }
  __syncthreads();
  float acc[16];
#pragma unroll
  for (int r = 0; r < 16; ++r) acc[r] = 0.f;
#pragma unroll 2
  for (int k = 0; k < 256; ++k) {
    float wv = W1[k * 256 + c];
    const float4* xr = (const float4*)&xsT[k][0];
    float4 x0 = xr[0], x1 = xr[1], x2 = xr[2], x3 = xr[3];
    acc[0] += x0.x * wv; acc[1] += x0.y * wv; acc[2] += x0.z * wv; acc[3] += x0.w * wv;
    acc[4] += x1.x * wv; acc[5] += x1.y * wv; acc[6] += x1.z * wv; acc[7] += x1.w * wv;
    acc[8] += x2.x * wv; acc[9] += x2.y * wv; acc[10] += x2.z * wv; acc[11] += x2.w * wv;
    acc[12] += x3.x * wv; acc[13] += x3.y * wv; acc[14] += x3.z * wv; acc[15] += x3.w * wv;
  }
  int head = c >> 6;
  float asv = as1[c];  // flat [head][c&63] == c
  float adv = ad1[c];
#pragma unroll
  for (int r = 0; r < 16; ++r) {
    h1[(base + r) * 256 + c] = acc[r];
    float vs = acc[r] * asv, vd = acc[r] * adv;
#pragma unroll
    for (int off = 32; off > 0; off >>= 1) {
      vs += __shfl_xor(vs, off);
      vd += __shfl_xor(vd, off);
    }
    if ((c & 63) == 0) {
      AS1[(base + r) * 4 + head] = vs;
      AD1[(base + r) * 4 + head] = vd;
    }
  }
}

// ---------------- GAT layer-1 aggregation + bias + ELU (fused) ----------------
__global__ __launch_bounds__(256) void k_agg1(
    const int* __restrict__ rp, const int* __restrict__ col,
    const float* __restrict__ h1, const float* __restrict__ AS1,
    const float* __restrict__ AD1, const float* __restrict__ b1,
    float* __restrict__ out) {
  int wave = threadIdx.x >> 6, lane = threadIdx.x & 63;
  int n = blockIdx.x * 4 + wave;
  int head = lane >> 4;
  int c4 = lane * 4;
  float adv = AD1[n * 4 + head];
  int e0 = rp[n], e1 = rp[n + 1];
  float ax = 0.f, ay = 0.f, az = 0.f, aw = 0.f, den = 0.f;
  for (int e = e0; e < e1; ++e) {
    int s = col[e];
    float ev = AS1[s * 4 + head] + adv;
    ev = ev > 0.f ? ev : NEG * ev;
    float p = __expf(ev);
    float4 hv = *(const float4*)(h1 + s * 256 + c4);
    ax += p * hv.x; ay += p * hv.y; az += p * hv.z; aw += p * hv.w;
    den += p;
  }
  float inv = 1.f / den;
  float4 bv = *(const float4*)(b1 + c4);
  float4 o;
  o.x = ax * inv + bv.x; o.y = ay * inv + bv.y;
  o.z = az * inv + bv.z; o.w = aw * inv + bv.w;
  o.x = o.x > 0.f ? o.x : __expf(o.x) - 1.f;
  o.y = o.y > 0.f ? o.y : __expf(o.y) - 1.f;
  o.z = o.z > 0.f ? o.z : __expf(o.z) - 1.f;
  o.w = o.w > 0.f ? o.w : __expf(o.w) - 1.f;
  *(float4*)(out + n * 256 + c4) = o;
}

// ---------------- GEMM2: h2 = h1act @ W2  [20000,256]x[256,64], + alphas ----------------
__global__ __launch_bounds__(256) void k_gemm2(
    const float* __restrict__ h1a, const float* __restrict__ W2,
    const float* __restrict__ as2, const float* __restrict__ ad2,
    float* __restrict__ h2, float* __restrict__ AS2, float* __restrict__ AD2) {
  __shared__ float xsT[256][20];
  int tid = threadIdx.x;
  int c = tid & 63, w = tid >> 6;  // wave w handles rows 4w..4w+3
  int base = blockIdx.x * 16;
  for (int i = tid; i < 16 * 256; i += 256) {
    int r = i >> 8, k = i & 255;
    xsT[k][r] = h1a[(base + r) * 256 + k];
  }
  __syncthreads();
  float acc[4] = {0.f, 0.f, 0.f, 0.f};
#pragma unroll 2
  for (int k = 0; k < 256; ++k) {
    float wv = W2[k * 64 + c];
    float4 xv = *(const float4*)&xsT[k][w * 4];
    acc[0] += xv.x * wv; acc[1] += xv.y * wv; acc[2] += xv.z * wv; acc[3] += xv.w * wv;
  }
  float asv = as2[c], adv = ad2[c];
#pragma unroll
  for (int rr = 0; rr < 4; ++rr) {
    int row = base + w * 4 + rr;
    h2[row * 64 + c] = acc[rr];
    float vs = acc[rr] * asv, vd = acc[rr] * adv;
#pragma unroll
    for (int off = 32; off > 0; off >>= 1) {
      vs += __shfl_xor(vs, off);
      vd += __shfl_xor(vd, off);
    }
    if (c == 0) { AS2[row] = vs; AD2[row] = vd; }
  }
}

// ---------------- GAT layer-2 aggregation + bias + ELU (fused) ----------------
__global__ __launch_bounds__(256) void k_agg2(
    const int* __restrict__ rp, const int* __restrict__ col,
    const float* __restrict__ h2, const float* __restrict__ AS2,
    const float* __restrict__ AD2, const float* __restrict__ b2,
    float* __restrict__ out) {
  int wave = threadIdx.x >> 6, lane = threadIdx.x & 63;
  int n = blockIdx.x * 4 + wave;
  float adv = AD2[n];
  int e0 = rp[n], e1 = rp[n + 1];
  float acc = 0.f, den = 0.f;
  for (int e = e0; e < e1; ++e) {
    int s = col[e];
    float ev = AS2[s] + adv;
    ev = ev > 0.f ? ev : NEG * ev;
    float p = __expf(ev);
    acc += p * h2[s * 64 + lane];
    den += p;
  }
  float v = acc / den + b2[lane];
  out[n * 64 + lane] = v > 0.f ? v : __expf(v) - 1.f;
}

// ---------------- pair MLP v5: small reg arrays + LDS z + s_load-batched weights ----------
// Lessons from rounds 1/3/4:
//  - z[64] in VGPRs => allocator spills regardless of launch_bounds. Cap per-thread
//    arrays at acc[32]+ck[16] (~56 live) so spilling is impossible by construction.
//  - Weight reads must be thread-uniform with the COMPILE-TIME index walking
//    consecutive floats -> batched s_load_dwordx16, dual-issued with v_fmac.
//    (Round 3's transposed Wp1 strode 512B and serialized the scalar pipe.)
//  - z parked in LDS transposed [t][pair], stride 130 floats -> bank (2t+tid)%32,
//    2-way aliasing = free. Each thread touches only column tid: no barriers.
#define PB 128  // threads (pairs) per block = 2 waves; LDS = 64*130*4 = 33.3 KB

__global__ __launch_bounds__(PB, 4) void k_pairs(
    const int* __restrict__ pairs, const float* __restrict__ h2a,
    const float* __restrict__ Wp1, const float* __restrict__ bp1,
    const float* __restrict__ Wp2, const float* __restrict__ bp2,
    float* __restrict__ out) {
  __shared__ float zt[64][PB + 2];  // [t][pair]
  int tid = threadIdx.x;
  int p = blockIdx.x * PB + tid;
  bool act = p < NP;
  int pc = act ? p : 0;
  int pi = pairs[2 * pc], pj = pairs[2 * pc + 1];
  const float* rowi = h2a + pi * 64;
  const float* rowj = h2a + pj * 64;

  // layer 1: z[t] = relu(bp1[t] + sum_k comb[k]*Wp1[k][t]), t in two halves of 32
#pragma unroll 1
  for (int h = 0; h < 2; ++h) {
    float acc[32];
#pragma unroll
    for (int u = 0; u < 32; ++u) acc[u] = bp1[h * 32 + u];
#pragma unroll 1
    for (int g = 0; g < 8; ++g) {  // 8 chunks of 16 k over comb(128)=[rowi,rowj]
      const float* src = (g < 4) ? rowi : rowj;
      int off = (g & 3) * 16;
      float ck[16];
#pragma unroll
      for (int q = 0; q < 4; ++q) {
        float4 v = *(const float4*)(src + off + q * 4);
        ck[q * 4] = v.x; ck[q * 4 + 1] = v.y; ck[q * 4 + 2] = v.z; ck[q * 4 + 3] = v.w;
      }
      int k0 = g * 16;
#pragma unroll
      for (int kk = 0; kk < 16; ++kk)
#pragma unroll
        for (int u = 0; u < 32; ++u)
          acc[u] += ck[kk] * Wp1[(k0 + kk) * 64 + h * 32 + u];  // uniform, u-consecutive
    }
#pragma unroll
    for (int u = 0; u < 32; ++u) zt[h * 32 + u][tid] = fmaxf(acc[u], 0.f);
  }

  // layer 2: out[p][o] = bp2[o] + sum_t z[t]*Wp2[t][o], two chunks of 43 cols
#pragma unroll 1
  for (int cch = 0; cch < 2; ++cch) {
    int o0 = cch * 43;
    float acc2[43];
#pragma unroll
    for (int j = 0; j < 43; ++j) acc2[j] = bp2[o0 + j];
#pragma unroll 2
    for (int t = 0; t < 64; ++t) {
      float zv = zt[t][tid];
#pragma unroll
      for (int j = 0; j < 43; ++j)
        acc2[j] += zv * Wp2[t * 86 + o0 + j];  // uniform, j-consecutive -> s_load_dwordx16
    }
    if (act) {
#pragma unroll
      for (int j = 0; j < 43; ++j) out[p * 86 + o0 + j] = acc2[j];
    }
  }
}

extern "C" void kernel_launch(void* const* d_in, const int* in_sizes, int n_in,
                              void* d_out, int out_size, void* d_ws, size_t ws_size,
                              hipStream_t stream) {
  (void)in_sizes; (void)n_in; (void)out_size; (void)ws_size;
  const float* x      = (const float*)d_in[0];
  const int*   ei     = (const int*)d_in[1];
  const int*   pairs  = (const int*)d_in[2];
  const float* W1     = (const float*)d_in[3];
  const float* a_src1 = (const float*)d_in[4];
  const float* a_dst1 = (const float*)d_in[5];
  const float* b1     = (const float*)d_in[6];
  const float* W2     = (const float*)d_in[7];
  const float* a_src2 = (const float*)d_in[8];
  const float* a_dst2 = (const float*)d_in[9];
  const float* b2     = (const float*)d_in[10];
  const float* Wp1    = (const float*)d_in[11];
  const float* bp1    = (const float*)d_in[12];
  const float* Wp2    = (const float*)d_in[13];
  const float* bp2    = (const float*)d_in[14];
  float* out = (float*)d_out;

  char* w = (char*)d_ws;
  auto alloc = [&](size_t bytes) -> void* {
    void* pp = (void*)w;
    w += (bytes + 255) & ~(size_t)255;
    return pp;
  };
  float* h1    = (float*)alloc((size_t)NN * 256 * 4);
  float* AS1   = (float*)alloc((size_t)NN * 4 * 4);
  float* AD1   = (float*)alloc((size_t)NN * 4 * 4);
  float* h1agg = (float*)alloc((size_t)NN * 256 * 4);
  float* h2    = (float*)alloc((size_t)NN * 64 * 4);
  float* AS2   = (float*)alloc((size_t)NN * 4);
  float* AD2   = (float*)alloc((size_t)NN * 4);
  float* h2agg = (float*)alloc((size_t)NN * 64 * 4);
  int*   rp    = (int*)alloc((size_t)(NN + 1) * 4);
  int*   cnt   = (int*)alloc((size_t)NN * 4);
  int*   cur   = (int*)alloc((size_t)NN * 4);
  int*   col   = (int*)alloc((size_t)NEE * 4);

  hipMemsetAsync(cnt, 0, (size_t)NN * 4, stream);
  hipMemsetAsync(cur, 0, (size_t)NN * 4, stream);

  const int EB = (NEE + 255) / 256;  // 2579
  k_hist<<<EB, 256, 0, stream>>>(ei, cnt);
  k_scan<<<1, 256, 0, stream>>>(cnt, rp);
  k_scatter<<<EB, 256, 0, stream>>>(ei, rp, cur, col);

  k_gemm1<<<NN / 16, 256, 0, stream>>>(x, W1, a_src1, a_dst1, h1, AS1, AD1);
  k_agg1<<<NN / 4, 256, 0, stream>>>(rp, col, h1, AS1, AD1, b1, h1agg);

  k_gemm2<<<NN / 16, 256, 0, stream>>>(h1agg, W2, a_src2, a_dst2, h2, AS2, AD2);
  k_agg2<<<NN / 4, 256, 0, stream>>>(rp, col, h2, AS2, AD2, b2, h2agg);

  k_pairs<<<(NP + PB - 1) / PB, PB, 0, stream>>>(pairs, h2agg, Wp1, bp1, Wp2, bp2, out);
}

// Round 6
// 478.434 us; speedup vs baseline: 1.5654x; 1.0726x over previous
//
#include <hip/hip_runtime.h>

#define NN 20000      // nodes
#define NE 640000     // edges (without self loops)
#define NEE 660000    // edges + self loops
#define NP 200000     // drug pairs
#define NEG 0.2f      // leaky relu slope

// ---------------- CSR build ----------------
__global__ void k_hist(const int* __restrict__ ei, int* __restrict__ cnt) {
  int i = blockIdx.x * 256 + threadIdx.x;
  if (i >= NEE) return;
  int d = (i < NE) ? ei[NE + i] : (i - NE);
  atomicAdd(&cnt[d], 1);
}

__global__ void k_scan(const int* __restrict__ cnt, int* __restrict__ rp) {
  __shared__ int ps[256];
  const int CH = 79;  // 79*256 = 20224 >= 20000
  int t = threadIdx.x;
  int lo = t * CH, hi = lo + CH;
  if (hi > NN) hi = NN;
  if (lo > NN) lo = NN;
  int s = 0;
  for (int i = lo; i < hi; ++i) s += cnt[i];
  ps[t] = s;
  __syncthreads();
  for (int off = 1; off < 256; off <<= 1) {
    int v = (t >= off) ? ps[t - off] : 0;
    __syncthreads();
    ps[t] += v;
    __syncthreads();
  }
  int run = (t > 0) ? ps[t - 1] : 0;
  for (int i = lo; i < hi; ++i) { rp[i] = run; run += cnt[i]; }
  if (t == 255) rp[NN] = ps[255];
}

__global__ void k_scatter(const int* __restrict__ ei, const int* __restrict__ rp,
                          int* __restrict__ cur, int* __restrict__ col,
                          int* __restrict__ dstv) {
  int i = blockIdx.x * 256 + threadIdx.x;
  if (i >= NEE) return;
  int s, d;
  if (i < NE) { s = ei[i]; d = ei[NE + i]; } else { s = i - NE; d = s; }
  int pos = atomicAdd(&cur[d], 1);
  col[rp[d] + pos] = s;
  dstv[rp[d] + pos] = d;
}

// ---------------- GEMM1: h1 = x @ W1  [20000,256]x[256,256], + alphas ----------------
__global__ __launch_bounds__(256) void k_gemm1(
    const float* __restrict__ x, const float* __restrict__ W1,
    const float* __restrict__ as1, const float* __restrict__ ad1,
    float* __restrict__ h1, float* __restrict__ AS1, float* __restrict__ AD1) {
  __shared__ float xsT[256][20];  // [k][row], pad 20 keeps 16B row alignment
  int c = threadIdx.x;            // output col 0..255
  int base = blockIdx.x * 16;     // 16 rows per block
  for (int i = threadIdx.x; i < 16 * 256; i += 256) {
    int r = i >> 8, k = i & 255;
    xsT[k][r] = x[(base + r) * 256 + k];
  }
  __syncthreads();
  float acc[16];
#pragma unroll
  for (int r = 0; r < 16; ++r) acc[r] = 0.f;
#pragma unroll 2
  for (int k = 0; k < 256; ++k) {
    float wv = W1[k * 256 + c];
    const float4* xr = (const float4*)&xsT[k][0];
    float4 x0 = xr[0], x1 = xr[1], x2 = xr[2], x3 = xr[3];
    acc[0] += x0.x * wv; acc[1] += x0.y * wv; acc[2] += x0.z * wv; acc[3] += x0.w * wv;
    acc[4] += x1.x * wv; acc[5] += x1.y * wv; acc[6] += x1.z * wv; acc[7] += x1.w * wv;
    acc[8] += x2.x * wv; acc[9] += x2.y * wv; acc[10] += x2.z * wv; acc[11] += x2.w * wv;
    acc[12] += x3.x * wv; acc[13] += x3.y * wv; acc[14] += x3.z * wv; acc[15] += x3.w * wv;
  }
  int head = c >> 6;
  float asv = as1[c];  // flat [head][c&63] == c
  float adv = ad1[c];
#pragma unroll
  for (int r = 0; r < 16; ++r) {
    h1[(base + r) * 256 + c] = acc[r];
    float vs = acc[r] * asv, vd = acc[r] * adv;
#pragma unroll
    for (int off = 32; off > 0; off >>= 1) {
      vs += __shfl_xor(vs, off);
      vd += __shfl_xor(vd, off);
    }
    if ((c & 63) == 0) {
      AS1[(base + r) * 4 + head] = vs;
      AD1[(base + r) * 4 + head] = vd;
    }
  }
}

// ---------------- edge weights layer 1: p = exp(lrelu(AS1[s]+AD1[d])), 4 heads ------------
__global__ void k_edgew1(const int* __restrict__ col, const int* __restrict__ dstv,
                         const float* __restrict__ AS1, const float* __restrict__ AD1,
                         float* __restrict__ w1) {
  int i = blockIdx.x * 256 + threadIdx.x;
  if (i >= NEE) return;
  int s = col[i], d = dstv[i];
  float4 as = *(const float4*)(AS1 + s * 4);
  float4 ad = *(const float4*)(AD1 + d * 4);
  float e0 = as.x + ad.x, e1 = as.y + ad.y, e2 = as.z + ad.z, e3 = as.w + ad.w;
  e0 = e0 > 0.f ? e0 : NEG * e0;
  e1 = e1 > 0.f ? e1 : NEG * e1;
  e2 = e2 > 0.f ? e2 : NEG * e2;
  e3 = e3 > 0.f ? e3 : NEG * e3;
  w1[0 * NEE + i] = __expf(e0);
  w1[1 * NEE + i] = __expf(e1);
  w1[2 * NEE + i] = __expf(e2);
  w1[3 * NEE + i] = __expf(e3);
}

// ---------------- GAT layer-1 aggregation, per-head pass, + bias + ELU -------------------
// grid = (NN/4, 4); pass head reads only its 5 MB column slice of h1 (L2-class)
__global__ __launch_bounds__(256) void k_agg1(
    const int* __restrict__ rp, const int* __restrict__ col,
    const float* __restrict__ w1, const float* __restrict__ h1,
    const float* __restrict__ b1, float* __restrict__ out) {
  int wave = threadIdx.x >> 6, lane = threadIdx.x & 63;
  int head = blockIdx.y;
  int n = blockIdx.x * 4 + wave;
  int e0 = rp[n], e1 = rp[n + 1];
  const float* hs = h1 + head * 64 + lane;
  const float* wp = w1 + head * NEE;
  float acc = 0.f, den = 0.f;
  int e = e0;
  for (; e + 1 < e1; e += 2) {
    int s0 = col[e], s1 = col[e + 1];
    float p0 = wp[e], p1 = wp[e + 1];
    float v0 = hs[(size_t)s0 * 256];
    float v1 = hs[(size_t)s1 * 256];
    acc += p0 * v0; den += p0;
    acc += p1 * v1; den += p1;
  }
  if (e < e1) {
    int s0 = col[e];
    float p0 = wp[e];
    acc += p0 * hs[(size_t)s0 * 256];
    den += p0;
  }
  float r = acc / den + b1[head * 64 + lane];
  out[n * 256 + head * 64 + lane] = r > 0.f ? r : __expf(r) - 1.f;
}

// ---------------- GEMM2: h2 = h1act @ W2  [20000,256]x[256,64], + alphas ----------------
__global__ __launch_bounds__(256) void k_gemm2(
    const float* __restrict__ h1a, const float* __restrict__ W2,
    const float* __restrict__ as2, const float* __restrict__ ad2,
    float* __restrict__ h2, float* __restrict__ AS2, float* __restrict__ AD2) {
  __shared__ float xsT[256][20];
  int tid = threadIdx.x;
  int c = tid & 63, w = tid >> 6;  // wave w handles rows 4w..4w+3
  int base = blockIdx.x * 16;
  for (int i = tid; i < 16 * 256; i += 256) {
    int r = i >> 8, k = i & 255;
    xsT[k][r] = h1a[(base + r) * 256 + k];
  }
  __syncthreads();
  float acc[4] = {0.f, 0.f, 0.f, 0.f};
#pragma unroll 2
  for (int k = 0; k < 256; ++k) {
    float wv = W2[k * 64 + c];
    float4 xv = *(const float4*)&xsT[k][w * 4];
    acc[0] += xv.x * wv; acc[1] += xv.y * wv; acc[2] += xv.z * wv; acc[3] += xv.w * wv;
  }
  float asv = as2[c], adv = ad2[c];
#pragma unroll
  for (int rr = 0; rr < 4; ++rr) {
    int row = base + w * 4 + rr;
    h2[row * 64 + c] = acc[rr];
    float vs = acc[rr] * asv, vd = acc[rr] * adv;
#pragma unroll
    for (int off = 32; off > 0; off >>= 1) {
      vs += __shfl_xor(vs, off);
      vd += __shfl_xor(vd, off);
    }
    if (c == 0) { AS2[row] = vs; AD2[row] = vd; }
  }
}

// ---------------- edge weights layer 2 ----------------
__global__ void k_edgew2(const int* __restrict__ col, const int* __restrict__ dstv,
                         const float* __restrict__ AS2, const float* __restrict__ AD2,
                         float* __restrict__ w2) {
  int i = blockIdx.x * 256 + threadIdx.x;
  if (i >= NEE) return;
  int s = col[i], d = dstv[i];
  float ev = AS2[s] + AD2[d];
  ev = ev > 0.f ? ev : NEG * ev;
  w2[i] = __expf(ev);
}

// ---------------- GAT layer-2 aggregation + bias + ELU ----------------
__global__ __launch_bounds__(256) void k_agg2(
    const int* __restrict__ rp, const int* __restrict__ col,
    const float* __restrict__ w2, const float* __restrict__ h2,
    const float* __restrict__ b2, float* __restrict__ out) {
  int wave = threadIdx.x >> 6, lane = threadIdx.x & 63;
  int n = blockIdx.x * 4 + wave;
  int e0 = rp[n], e1 = rp[n + 1];
  float acc = 0.f, den = 0.f;
  int e = e0;
  for (; e + 1 < e1; e += 2) {
    int s0 = col[e], s1 = col[e + 1];
    float p0 = w2[e], p1 = w2[e + 1];
    float v0 = h2[(size_t)s0 * 64 + lane];
    float v1 = h2[(size_t)s1 * 64 + lane];
    acc += p0 * v0; den += p0;
    acc += p1 * v1; den += p1;
  }
  if (e < e1) {
    int s0 = col[e];
    float p0 = w2[e];
    acc += p0 * h2[(size_t)s0 * 64 + lane];
    den += p0;
  }
  float v = acc / den + b2[lane];
  out[n * 64 + lane] = v > 0.f ? v : __expf(v) - 1.f;
}

// ---------------- pair MLP v6: pair split across 2 waves, LDS z, scalar weights ----------
// Block = 128 threads = 2 waves, 64 pairs. Wave h computes z-half h (32 u's) for
// all 64 pairs, then output-column chunk h (43 cols). Per-thread live arrays are
// acc[32] / acc2[43] (spill-proof, proven round-5 shape). Weight addresses use
// hu = readfirstlane(wave-id) so the compiler PROVES uniformity -> s_load batches.
// LDS z is [t][pair] (stride 66 -> 2-way bank aliasing, free). 16.9 KB -> 9 blocks/CU.
#define PB 128

__global__ __launch_bounds__(PB) void k_pairs(
    const int* __restrict__ pairs, const float* __restrict__ h2a,
    const float* __restrict__ Wp1, const float* __restrict__ bp1,
    const float* __restrict__ Wp2, const float* __restrict__ bp2,
    float* __restrict__ out) {
  __shared__ float zt[64][66];  // [t][pair]
  int tid = threadIdx.x;
  int pp = tid & 63;                                      // pair within block
  int hu = __builtin_amdgcn_readfirstlane(tid >> 6);      // wave id, provably uniform
  int p = blockIdx.x * 64 + pp;
  bool act = p < NP;
  int pc = act ? p : 0;
  int pi = pairs[2 * pc], pj = pairs[2 * pc + 1];
  const float* rowi = h2a + pi * 64;
  const float* rowj = h2a + pj * 64;

  // layer 1: z[hu*32+u] = relu(bp1 + sum_k comb[k]*Wp1[k][hu*32+u])
  {
    float acc[32];
#pragma unroll
    for (int u = 0; u < 32; ++u) acc[u] = bp1[hu * 32 + u];
#pragma unroll 1
    for (int g = 0; g < 8; ++g) {  // 8 chunks of 16 k over comb(128)=[rowi,rowj]
      const float* src = (g < 4) ? rowi : rowj;
      int off = (g & 3) * 16;
      float ck[16];
#pragma unroll
      for (int q = 0; q < 4; ++q) {
        float4 v = *(const float4*)(src + off + q * 4);
        ck[q * 4] = v.x; ck[q * 4 + 1] = v.y; ck[q * 4 + 2] = v.z; ck[q * 4 + 3] = v.w;
      }
      int k0 = g * 16;
#pragma unroll
      for (int kk = 0; kk < 16; ++kk)
#pragma unroll
        for (int u = 0; u < 32; ++u)
          acc[u] += ck[kk] * Wp1[(k0 + kk) * 64 + hu * 32 + u];  // uniform, u-consecutive
    }
#pragma unroll
    for (int u = 0; u < 32; ++u) zt[hu * 32 + u][pp] = fmaxf(acc[u], 0.f);
  }
  __syncthreads();

  // layer 2: out[p][hu*43 + j] = bp2 + sum_t z[t]*Wp2[t][hu*43+j], 43 cols per wave
  {
    float acc2[43];
#pragma unroll
    for (int j = 0; j < 43; ++j) acc2[j] = bp2[hu * 43 + j];
#pragma unroll 2
    for (int t = 0; t < 64; ++t) {
      float zv = zt[t][pp];
#pragma unroll
      for (int j = 0; j < 43; ++j)
        acc2[j] += zv * Wp2[t * 86 + hu * 43 + j];  // uniform, j-consecutive
    }
    if (act) {
#pragma unroll
      for (int j = 0; j < 43; ++j) out[p * 86 + hu * 43 + j] = acc2[j];
    }
  }
}

extern "C" void kernel_launch(void* const* d_in, const int* in_sizes, int n_in,
                              void* d_out, int out_size, void* d_ws, size_t ws_size,
                              hipStream_t stream) {
  (void)in_sizes; (void)n_in; (void)out_size; (void)ws_size;
  const float* x      = (const float*)d_in[0];
  const int*   ei     = (const int*)d_in[1];
  const int*   pairs  = (const int*)d_in[2];
  const float* W1     = (const float*)d_in[3];
  const float* a_src1 = (const float*)d_in[4];
  const float* a_dst1 = (const float*)d_in[5];
  const float* b1     = (const float*)d_in[6];
  const float* W2     = (const float*)d_in[7];
  const float* a_src2 = (const float*)d_in[8];
  const float* a_dst2 = (const float*)d_in[9];
  const float* b2     = (const float*)d_in[10];
  const float* Wp1    = (const float*)d_in[11];
  const float* bp1    = (const float*)d_in[12];
  const float* Wp2    = (const float*)d_in[13];
  const float* bp2    = (const float*)d_in[14];
  float* out = (float*)d_out;

  char* w = (char*)d_ws;
  auto alloc = [&](size_t bytes) -> void* {
    void* pp = (void*)w;
    w += (bytes + 255) & ~(size_t)255;
    return pp;
  };
  float* h1    = (float*)alloc((size_t)NN * 256 * 4);
  float* AS1   = (float*)alloc((size_t)NN * 4 * 4);
  float* AD1   = (float*)alloc((size_t)NN * 4 * 4);
  float* h1agg = (float*)alloc((size_t)NN * 256 * 4);
  float* h2    = (float*)alloc((size_t)NN * 64 * 4);
  float* AS2   = (float*)alloc((size_t)NN * 4);
  float* AD2   = (float*)alloc((size_t)NN * 4);
  float* h2agg = (float*)alloc((size_t)NN * 64 * 4);
  int*   rp    = (int*)alloc((size_t)(NN + 1) * 4);
  int*   cnt   = (int*)alloc((size_t)NN * 4);
  int*   cur   = (int*)alloc((size_t)NN * 4);
  int*   col   = (int*)alloc((size_t)NEE * 4);
  int*   dstv  = (int*)alloc((size_t)NEE * 4);
  float* w1    = (float*)alloc((size_t)4 * NEE * 4);
  float* w2    = (float*)alloc((size_t)NEE * 4);

  hipMemsetAsync(cnt, 0, (size_t)NN * 4, stream);
  hipMemsetAsync(cur, 0, (size_t)NN * 4, stream);

  const int EB = (NEE + 255) / 256;  // 2579
  k_hist<<<EB, 256, 0, stream>>>(ei, cnt);
  k_scan<<<1, 256, 0, stream>>>(cnt, rp);
  k_scatter<<<EB, 256, 0, stream>>>(ei, rp, cur, col, dstv);

  k_gemm1<<<NN / 16, 256, 0, stream>>>(x, W1, a_src1, a_dst1, h1, AS1, AD1);
  k_edgew1<<<EB, 256, 0, stream>>>(col, dstv, AS1, AD1, w1);
  k_agg1<<<dim3(NN / 4, 4), 256, 0, stream>>>(rp, col, w1, h1, b1, h1agg);

  k_gemm2<<<NN / 16, 256, 0, stream>>>(h1agg, W2, a_src2, a_dst2, h2, AS2, AD2);
  k_edgew2<<<EB, 256, 0, stream>>>(col, dstv, AS2, AD2, w2);
  k_agg2<<<NN / 4, 256, 0, stream>>>(rp, col, w2, h2, b2, h2agg);

  k_pairs<<<(NP + 63) / 64, PB, 0, stream>>>(pairs, h2agg, Wp1, bp1, Wp2, bp2, out);
}

// Round 7
// 399.788 us; speedup vs baseline: 1.8733x; 1.1967x over previous
//
#include <hip/hip_runtime.h>

#define NN 20000      // nodes
#define NE 640000     // edges (without self loops)
#define NEE 660000    // edges + self loops
#define NP 200000     // drug pairs
#define NEG 0.2f      // leaky relu slope

// ---------------- CSR build ----------------
__global__ void k_hist(const int* __restrict__ ei, int* __restrict__ cnt) {
  int i = blockIdx.x * 256 + threadIdx.x;
  if (i >= NEE) return;
  int d = (i < NE) ? ei[NE + i] : (i - NE);
  atomicAdd(&cnt[d], 1);
}

__global__ void k_scan(const int* __restrict__ cnt, int* __restrict__ rp) {
  __shared__ int ps[256];
  const int CH = 79;  // 79*256 = 20224 >= 20000
  int t = threadIdx.x;
  int lo = t * CH, hi = lo + CH;
  if (hi > NN) hi = NN;
  if (lo > NN) lo = NN;
  int s = 0;
  for (int i = lo; i < hi; ++i) s += cnt[i];
  ps[t] = s;
  __syncthreads();
  for (int off = 1; off < 256; off <<= 1) {
    int v = (t >= off) ? ps[t - off] : 0;
    __syncthreads();
    ps[t] += v;
    __syncthreads();
  }
  int run = (t > 0) ? ps[t - 1] : 0;
  for (int i = lo; i < hi; ++i) { rp[i] = run; run += cnt[i]; }
  if (t == 255) rp[NN] = ps[255];
}

__global__ void k_scatter(const int* __restrict__ ei, const int* __restrict__ rp,
                          int* __restrict__ cur, int* __restrict__ col,
                          int* __restrict__ dstv) {
  int i = blockIdx.x * 256 + threadIdx.x;
  if (i >= NEE) return;
  int s, d;
  if (i < NE) { s = ei[i]; d = ei[NE + i]; } else { s = i - NE; d = s; }
  int pos = atomicAdd(&cur[d], 1);
  col[rp[d] + pos] = s;
  dstv[rp[d] + pos] = d;
}

// ---------------- GEMM1: h1 = x @ W1  [20000,256]x[256,256], + alphas ----------------
// h1 is stored HEAD-MAJOR: h1h[head][n][64] so each head's slice is a contiguous 5 MB.
__global__ __launch_bounds__(256) void k_gemm1(
    const float* __restrict__ x, const float* __restrict__ W1,
    const float* __restrict__ as1, const float* __restrict__ ad1,
    float* __restrict__ h1h, float* __restrict__ AS1, float* __restrict__ AD1) {
  __shared__ float xsT[256][20];  // [k][row], pad 20 keeps 16B row alignment
  int c = threadIdx.x;            // output col 0..255
  int base = blockIdx.x * 16;     // 16 rows per block
  for (int i = threadIdx.x; i < 16 * 256; i += 256) {
    int r = i >> 8, k = i & 255;
    xsT[k][r] = x[(base + r) * 256 + k];
  }
  __syncthreads();
  float acc[16];
#pragma unroll
  for (int r = 0; r < 16; ++r) acc[r] = 0.f;
#pragma unroll 2
  for (int k = 0; k < 256; ++k) {
    float wv = W1[k * 256 + c];
    const float4* xr = (const float4*)&xsT[k][0];
    float4 x0 = xr[0], x1 = xr[1], x2 = xr[2], x3 = xr[3];
    acc[0] += x0.x * wv; acc[1] += x0.y * wv; acc[2] += x0.z * wv; acc[3] += x0.w * wv;
    acc[4] += x1.x * wv; acc[5] += x1.y * wv; acc[6] += x1.z * wv; acc[7] += x1.w * wv;
    acc[8] += x2.x * wv; acc[9] += x2.y * wv; acc[10] += x2.z * wv; acc[11] += x2.w * wv;
    acc[12] += x3.x * wv; acc[13] += x3.y * wv; acc[14] += x3.z * wv; acc[15] += x3.w * wv;
  }
  int head = c >> 6, cc = c & 63;
  float asv = as1[c];  // flat [head][c&63] == c
  float adv = ad1[c];
#pragma unroll
  for (int r = 0; r < 16; ++r) {
    h1h[((size_t)head * NN + (base + r)) * 64 + cc] = acc[r];
    float vs = acc[r] * asv, vd = acc[r] * adv;
#pragma unroll
    for (int off = 32; off > 0; off >>= 1) {
      vs += __shfl_xor(vs, off);
      vd += __shfl_xor(vd, off);
    }
    if ((c & 63) == 0) {
      AS1[(base + r) * 4 + head] = vs;
      AD1[(base + r) * 4 + head] = vd;
    }
  }
}

// ---------------- edge weights layer 1: p = exp(lrelu(AS1[s]+AD1[d])), 4 heads ------------
__global__ void k_edgew1(const int* __restrict__ col, const int* __restrict__ dstv,
                         const float* __restrict__ AS1, const float* __restrict__ AD1,
                         float* __restrict__ w1) {
  int i = blockIdx.x * 256 + threadIdx.x;
  if (i >= NEE) return;
  int s = col[i], d = dstv[i];
  float4 as = *(const float4*)(AS1 + s * 4);
  float4 ad = *(const float4*)(AD1 + d * 4);
  float e0 = as.x + ad.x, e1 = as.y + ad.y, e2 = as.z + ad.z, e3 = as.w + ad.w;
  e0 = e0 > 0.f ? e0 : NEG * e0;
  e1 = e1 > 0.f ? e1 : NEG * e1;
  e2 = e2 > 0.f ? e2 : NEG * e2;
  e3 = e3 > 0.f ? e3 : NEG * e3;
  w1[0 * NEE + i] = __expf(e0);
  w1[1 * NEE + i] = __expf(e1);
  w1[2 * NEE + i] = __expf(e2);
  w1[3 * NEE + i] = __expf(e3);
}

// ---------------- GAT layer-1 aggregation: 4 edges x 16 lanes per wave ----------------
// grid = (NN/4, 4). Wave owns node n, head = blockIdx.y. Lane group g=lane>>4 owns
// edge e+g; lanes 0-15 of the group cover the 64-col head slice via float4 (1 KB
// moved per gather instruction per wave). Cross-group combine: shfl_xor(16|32).
__global__ __launch_bounds__(256) void k_agg1(
    const int* __restrict__ rp, const int* __restrict__ col,
    const float* __restrict__ w1, const float* __restrict__ h1h,
    const float* __restrict__ b1, float* __restrict__ out) {
  int wave = threadIdx.x >> 6, lane = threadIdx.x & 63;
  int head = blockIdx.y;
  int n = blockIdx.x * 4 + wave;
  int g = lane >> 4, c4 = (lane & 15) * 4;
  int e0 = rp[n], e1 = rp[n + 1];
  const float* hs = h1h + (size_t)head * NN * 64;
  const float* wp = w1 + (size_t)head * NEE;
  float ax = 0.f, ay = 0.f, az = 0.f, aw = 0.f, den = 0.f;
#pragma unroll 2
  for (int e = e0; e < e1; e += 4) {
    int ee = e + g;
    bool valid = ee < e1;
    int ec = valid ? ee : e1 - 1;
    int s = col[ec];
    float p = valid ? wp[ec] : 0.f;
    float4 hv = *(const float4*)(hs + (size_t)s * 64 + c4);
    ax += p * hv.x; ay += p * hv.y; az += p * hv.z; aw += p * hv.w;
    den += p;
  }
  ax += __shfl_xor(ax, 16); ax += __shfl_xor(ax, 32);
  ay += __shfl_xor(ay, 16); ay += __shfl_xor(ay, 32);
  az += __shfl_xor(az, 16); az += __shfl_xor(az, 32);
  aw += __shfl_xor(aw, 16); aw += __shfl_xor(aw, 32);
  den += __shfl_xor(den, 16); den += __shfl_xor(den, 32);
  if (lane < 16) {
    float inv = 1.f / den;
    int cbase = head * 64 + c4;
    float4 bv = *(const float4*)(b1 + cbase);
    float4 o;
    o.x = ax * inv + bv.x; o.y = ay * inv + bv.y;
    o.z = az * inv + bv.z; o.w = aw * inv + bv.w;
    o.x = o.x > 0.f ? o.x : __expf(o.x) - 1.f;
    o.y = o.y > 0.f ? o.y : __expf(o.y) - 1.f;
    o.z = o.z > 0.f ? o.z : __expf(o.z) - 1.f;
    o.w = o.w > 0.f ? o.w : __expf(o.w) - 1.f;
    *(float4*)(out + (size_t)n * 256 + cbase) = o;
  }
}

// ---------------- GEMM2: h2 = h1act @ W2  [20000,256]x[256,64], + alphas ----------------
__global__ __launch_bounds__(256) void k_gemm2(
    const float* __restrict__ h1a, const float* __restrict__ W2,
    const float* __restrict__ as2, const float* __restrict__ ad2,
    float* __restrict__ h2, float* __restrict__ AS2, float* __restrict__ AD2) {
  __shared__ float xsT[256][20];
  int tid = threadIdx.x;
  int c = tid & 63, w = tid >> 6;  // wave w handles rows 4w..4w+3
  int base = blockIdx.x * 16;
  for (int i = tid; i < 16 * 256; i += 256) {
    int r = i >> 8, k = i & 255;
    xsT[k][r] = h1a[(base + r) * 256 + k];
  }
  __syncthreads();
  float acc[4] = {0.f, 0.f, 0.f, 0.f};
#pragma unroll 2
  for (int k = 0; k < 256; ++k) {
    float wv = W2[k * 64 + c];
    float4 xv = *(const float4*)&xsT[k][w * 4];
    acc[0] += xv.x * wv; acc[1] += xv.y * wv; acc[2] += xv.z * wv; acc[3] += xv.w * wv;
  }
  float asv = as2[c], adv = ad2[c];
#pragma unroll
  for (int rr = 0; rr < 4; ++rr) {
    int row = base + w * 4 + rr;
    h2[row * 64 + c] = acc[rr];
    float vs = acc[rr] * asv, vd = acc[rr] * adv;
#pragma unroll
    for (int off = 32; off > 0; off >>= 1) {
      vs += __shfl_xor(vs, off);
      vd += __shfl_xor(vd, off);
    }
    if (c == 0) { AS2[row] = vs; AD2[row] = vd; }
  }
}

// ---------------- edge weights layer 2 ----------------
__global__ void k_edgew2(const int* __restrict__ col, const int* __restrict__ dstv,
                         const float* __restrict__ AS2, const float* __restrict__ AD2,
                         float* __restrict__ w2) {
  int i = blockIdx.x * 256 + threadIdx.x;
  if (i >= NEE) return;
  int s = col[i], d = dstv[i];
  float ev = AS2[s] + AD2[d];
  ev = ev > 0.f ? ev : NEG * ev;
  w2[i] = __expf(ev);
}

// ---------------- GAT layer-2 aggregation: 4 edges x 16 lanes per wave ----------------
__global__ __launch_bounds__(256) void k_agg2(
    const int* __restrict__ rp, const int* __restrict__ col,
    const float* __restrict__ w2, const float* __restrict__ h2,
    const float* __restrict__ b2, float* __restrict__ out) {
  int wave = threadIdx.x >> 6, lane = threadIdx.x & 63;
  int n = blockIdx.x * 4 + wave;
  int g = lane >> 4, c4 = (lane & 15) * 4;
  int e0 = rp[n], e1 = rp[n + 1];
  float ax = 0.f, ay = 0.f, az = 0.f, aw = 0.f, den = 0.f;
#pragma unroll 2
  for (int e = e0; e < e1; e += 4) {
    int ee = e + g;
    bool valid = ee < e1;
    int ec = valid ? ee : e1 - 1;
    int s = col[ec];
    float p = valid ? w2[ec] : 0.f;
    float4 hv = *(const float4*)(h2 + (size_t)s * 64 + c4);
    ax += p * hv.x; ay += p * hv.y; az += p * hv.z; aw += p * hv.w;
    den += p;
  }
  ax += __shfl_xor(ax, 16); ax += __shfl_xor(ax, 32);
  ay += __shfl_xor(ay, 16); ay += __shfl_xor(ay, 32);
  az += __shfl_xor(az, 16); az += __shfl_xor(az, 32);
  aw += __shfl_xor(aw, 16); aw += __shfl_xor(aw, 32);
  den += __shfl_xor(den, 16); den += __shfl_xor(den, 32);
  if (lane < 16) {
    float inv = 1.f / den;
    float4 bv = *(const float4*)(b2 + c4);
    float4 o;
    o.x = ax * inv + bv.x; o.y = ay * inv + bv.y;
    o.z = az * inv + bv.z; o.w = aw * inv + bv.w;
    o.x = o.x > 0.f ? o.x : __expf(o.x) - 1.f;
    o.y = o.y > 0.f ? o.y : __expf(o.y) - 1.f;
    o.z = o.z > 0.f ? o.z : __expf(o.z) - 1.f;
    o.w = o.w > 0.f ? o.w : __expf(o.w) - 1.f;
    *(float4*)(out + (size_t)n * 64 + c4) = o;
  }
}

// ---------------- pair MLP v6: pair split across 2 waves, LDS z, scalar weights ----------
#define PB 128

__global__ __launch_bounds__(PB) void k_pairs(
    const int* __restrict__ pairs, const float* __restrict__ h2a,
    const float* __restrict__ Wp1, const float* __restrict__ bp1,
    const float* __restrict__ Wp2, const float* __restrict__ bp2,
    float* __restrict__ out) {
  __shared__ float zt[64][66];  // [t][pair]
  int tid = threadIdx.x;
  int pp = tid & 63;                                      // pair within block
  int hu = __builtin_amdgcn_readfirstlane(tid >> 6);      // wave id, provably uniform
  int p = blockIdx.x * 64 + pp;
  bool act = p < NP;
  int pc = act ? p : 0;
  int pi = pairs[2 * pc], pj = pairs[2 * pc + 1];
  const float* rowi = h2a + pi * 64;
  const float* rowj = h2a + pj * 64;

  // layer 1: z[hu*32+u] = relu(bp1 + sum_k comb[k]*Wp1[k][hu*32+u])
  {
    float acc[32];
#pragma unroll
    for (int u = 0; u < 32; ++u) acc[u] = bp1[hu * 32 + u];
#pragma unroll 1
    for (int g = 0; g < 8; ++g) {  // 8 chunks of 16 k over comb(128)=[rowi,rowj]
      const float* src = (g < 4) ? rowi : rowj;
      int off = (g & 3) * 16;
      float ck[16];
#pragma unroll
      for (int q = 0; q < 4; ++q) {
        float4 v = *(const float4*)(src + off + q * 4);
        ck[q * 4] = v.x; ck[q * 4 + 1] = v.y; ck[q * 4 + 2] = v.z; ck[q * 4 + 3] = v.w;
      }
      int k0 = g * 16;
#pragma unroll
      for (int kk = 0; kk < 16; ++kk)
#pragma unroll
        for (int u = 0; u < 32; ++u)
          acc[u] += ck[kk] * Wp1[(k0 + kk) * 64 + hu * 32 + u];  // uniform, u-consecutive
    }
#pragma unroll
    for (int u = 0; u < 32; ++u) zt[hu * 32 + u][pp] = fmaxf(acc[u], 0.f);
  }
  __syncthreads();

  // layer 2: out[p][hu*43 + j] = bp2 + sum_t z[t]*Wp2[t][hu*43+j], 43 cols per wave
  {
    float acc2[43];
#pragma unroll
    for (int j = 0; j < 43; ++j) acc2[j] = bp2[hu * 43 + j];
#pragma unroll 2
    for (int t = 0; t < 64; ++t) {
      float zv = zt[t][pp];
#pragma unroll
      for (int j = 0; j < 43; ++j)
        acc2[j] += zv * Wp2[t * 86 + hu * 43 + j];  // uniform, j-consecutive
    }
    if (act) {
#pragma unroll
      for (int j = 0; j < 43; ++j) out[p * 86 + hu * 43 + j] = acc2[j];
    }
  }
}

extern "C" void kernel_launch(void* const* d_in, const int* in_sizes, int n_in,
                              void* d_out, int out_size, void* d_ws, size_t ws_size,
                              hipStream_t stream) {
  (void)in_sizes; (void)n_in; (void)out_size; (void)ws_size;
  const float* x      = (const float*)d_in[0];
  const int*   ei     = (const int*)d_in[1];
  const int*   pairs  = (const int*)d_in[2];
  const float* W1     = (const float*)d_in[3];
  const float* a_src1 = (const float*)d_in[4];
  const float* a_dst1 = (const float*)d_in[5];
  const float* b1     = (const float*)d_in[6];
  const float* W2     = (const float*)d_in[7];
  const float* a_src2 = (const float*)d_in[8];
  const float* a_dst2 = (const float*)d_in[9];
  const float* b2     = (const float*)d_in[10];
  const float* Wp1    = (const float*)d_in[11];
  const float* bp1    = (const float*)d_in[12];
  const float* Wp2    = (const float*)d_in[13];
  const float* bp2    = (const float*)d_in[14];
  float* out = (float*)d_out;

  char* w = (char*)d_ws;
  auto alloc = [&](size_t bytes) -> void* {
    void* pp = (void*)w;
    w += (bytes + 255) & ~(size_t)255;
    return pp;
  };
  float* h1    = (float*)alloc((size_t)NN * 256 * 4);  // head-major [4][NN][64]
  float* AS1   = (float*)alloc((size_t)NN * 4 * 4);
  float* AD1   = (float*)alloc((size_t)NN * 4 * 4);
  float* h1agg = (float*)alloc((size_t)NN * 256 * 4);
  float* h2    = (float*)alloc((size_t)NN * 64 * 4);
  float* AS2   = (float*)alloc((size_t)NN * 4);
  float* AD2   = (float*)alloc((size_t)NN * 4);
  float* h2agg = (float*)alloc((size_t)NN * 64 * 4);
  int*   rp    = (int*)alloc((size_t)(NN + 1) * 4);
  int*   cnt   = (int*)alloc((size_t)NN * 4);
  int*   cur   = (int*)alloc((size_t)NN * 4);
  int*   col   = (int*)alloc((size_t)NEE * 4);
  int*   dstv  = (int*)alloc((size_t)NEE * 4);
  float* w1    = (float*)alloc((size_t)4 * NEE * 4);
  float* w2    = (float*)alloc((size_t)NEE * 4);

  hipMemsetAsync(cnt, 0, (size_t)NN * 4, stream);
  hipMemsetAsync(cur, 0, (size_t)NN * 4, stream);

  const int EB = (NEE + 255) / 256;  // 2579
  k_hist<<<EB, 256, 0, stream>>>(ei, cnt);
  k_scan<<<1, 256, 0, stream>>>(cnt, rp);
  k_scatter<<<EB, 256, 0, stream>>>(ei, rp, cur, col, dstv);

  k_gemm1<<<NN / 16, 256, 0, stream>>>(x, W1, a_src1, a_dst1, h1, AS1, AD1);
  k_edgew1<<<EB, 256, 0, stream>>>(col, dstv, AS1, AD1, w1);
  k_agg1<<<dim3(NN / 4, 4), 256, 0, stream>>>(rp, col, w1, h1, b1, h1agg);

  k_gemm2<<<NN / 16, 256, 0, stream>>>(h1agg, W2, a_src2, a_dst2, h2, AS2, AD2);
  k_edgew2<<<EB, 256, 0, stream>>>(col, dstv, AS2, AD2, w2);
  k_agg2<<<NN / 4, 256, 0, stream>>>(rp, col, w2, h2, b2, h2agg);

  k_pairs<<<(NP + 63) / 64, PB, 0, stream>>>(pairs, h2agg, Wp1, bp1, Wp2, bp2, out);
}